// Round 1
// baseline (369.989 us; speedup 1.0000x reference)
//
#include <hip/hip_runtime.h>
#include <math.h>

#define B_TOK 2048
#define DMODEL 1024
#define HDIM 4096
#define NEXP 8
#define TOPK 2

#define BM 128
#define BN 128
#define BK 64
#define MAX_TILES 40

typedef __attribute__((ext_vector_type(8))) short bf16x8;
typedef __attribute__((ext_vector_type(4))) float f32x4;

__device__ __forceinline__ unsigned short f2b(float f) {
  unsigned u = __builtin_bit_cast(unsigned, f);
  unsigned r = (u + 0x7FFFu + ((u >> 16) & 1u)) >> 16;
  return (unsigned short)r;
}

__device__ __forceinline__ void load_lds16(const void* g, void* l) {
  __builtin_amdgcn_global_load_lds(
      (const __attribute__((address_space(1))) unsigned int*)g,
      (__attribute__((address_space(3))) unsigned int*)l, 16, 0, 0);
}

// ---------------- gate: logits (f64 accum) -> top2 -> softmax ----------------
__global__ __launch_bounds__(256) void gate_kernel(
    const float* __restrict__ x, const float* __restrict__ gw,
    const float* __restrict__ gb, int* __restrict__ idx2,
    float* __restrict__ sc2, int* __restrict__ counts) {
  int lane = threadIdx.x & 63;
  int w = threadIdx.x >> 6;
  int b = blockIdx.x * 4 + w;
  double acc[NEXP];
#pragma unroll
  for (int e = 0; e < NEXP; ++e) acc[e] = 0.0;
  const float* xr = x + (size_t)b * DMODEL;
#pragma unroll
  for (int i = 0; i < 4; ++i) {
    float4 xv = *(const float4*)(xr + i * 256 + lane * 4);
#pragma unroll
    for (int e = 0; e < NEXP; ++e) {
      float4 wv = *(const float4*)(gw + e * DMODEL + i * 256 + lane * 4);
      acc[e] += (double)xv.x * wv.x + (double)xv.y * wv.y +
                (double)xv.z * wv.z + (double)xv.w * wv.w;
    }
  }
#pragma unroll
  for (int e = 0; e < NEXP; ++e) {
    double v = acc[e];
    for (int o = 1; o < 64; o <<= 1) v += __shfl_xor(v, o, 64);
    acc[e] = v + (double)gb[e];
  }
  if (lane == 0) {
    int i0 = 0;
    double v0 = acc[0];
#pragma unroll
    for (int e = 1; e < NEXP; ++e)
      if (acc[e] > v0) { v0 = acc[e]; i0 = e; }
    int i1 = -1;
    double v1 = -1e300;
#pragma unroll
    for (int e = 0; e < NEXP; ++e)
      if (e != i0 && acc[e] > v1) { v1 = acc[e]; i1 = e; }
    double t = exp(v1 - v0);
    float s0 = (float)(1.0 / (1.0 + t));
    float s1 = (float)(t / (1.0 + t));
    idx2[b * 2] = i0;
    idx2[b * 2 + 1] = i1;
    sc2[b * 2] = s0;
    sc2[b * 2 + 1] = s1;
    atomicAdd(&counts[i0], 1);
    atomicAdd(&counts[i1], 1);
  }
}

// ---------------- plan: prefix offsets + tile map (1 thread) ----------------
__global__ void plan_kernel(const int* __restrict__ counts, int* __restrict__ offsets,
                            int* __restrict__ tile_map, int* __restrict__ ntiles,
                            int* __restrict__ cursors) {
  int off = 0;
  offsets[0] = 0;
  for (int e = 0; e < NEXP; ++e) {
    off += counts[e];
    offsets[e + 1] = off;
    cursors[e] = 0;
  }
  int tt = 0;
  for (int e = 0; e < NEXP; ++e) {
    int cnt = counts[e];
    int base = offsets[e];
    for (int t = 0; t * BM < cnt; ++t) {
      tile_map[tt * 4 + 0] = e;
      tile_map[tt * 4 + 1] = base + t * BM;
      tile_map[tt * 4 + 2] = (cnt - t * BM) < BM ? (cnt - t * BM) : BM;
      tile_map[tt * 4 + 3] = 0;
      ++tt;
    }
  }
  *ntiles = tt;
}

// ---------------- scatter: (b,k) -> pos ----------------
__global__ __launch_bounds__(256) void scatter_kernel(
    const int* __restrict__ idx2, const int* __restrict__ offsets,
    int* __restrict__ cursors, int* __restrict__ pos_of, int* __restrict__ row_of) {
  int t = blockIdx.x * 256 + threadIdx.x;
  if (t < B_TOK * TOPK) {
    int e = idx2[t];
    int p = offsets[e] + atomicAdd(&cursors[e], 1);
    pos_of[t] = p;
    row_of[p] = t >> 1;
  }
}

// ---------------- gather: permuted bf16 activations ----------------
__global__ __launch_bounds__(256) void gather_kernel(
    const float* __restrict__ x, const int* __restrict__ row_of,
    unsigned short* __restrict__ Xp) {
  int r = blockIdx.x;
  int tok = row_of[r];
  int c = threadIdx.x * 4;
  float4 v = *(const float4*)(x + (size_t)tok * DMODEL + c);
  ushort4 o = make_ushort4(f2b(v.x), f2b(v.y), f2b(v.z), f2b(v.w));
  *(ushort4*)(Xp + (size_t)r * DMODEL + c) = o;
}

// ---------------- grouped GEMM: C[rows,N] = A[rows,K](bf16) * B[K,N](f32->bf16) + bias ----------------
template <bool GELU, bool OUTBF16>
__global__ __launch_bounds__(256) void gemm_kernel(
    const unsigned short* __restrict__ A, int lda, const float* __restrict__ Bw,
    long strideB, int ldb, const float* __restrict__ bias, int strideBias,
    void* __restrict__ Cout, int ldc, const int* __restrict__ tile_map,
    const int* __restrict__ ntiles, int N, int K) {
  const int nb = N / BN;
  const int tile = blockIdx.x / nb;
  if (tile >= *ntiles) return;
  const int ct = blockIdx.x % nb;
  const int e = tile_map[tile * 4 + 0];
  const int row0 = tile_map[tile * 4 + 1];
  const int rows = tile_map[tile * 4 + 2];
  const float* B_e = Bw + (long)e * strideB;
  const int n0 = ct * BN;

  __shared__ __align__(16) unsigned short Asm[BM * BK];
  __shared__ __align__(16) unsigned short Bsm[BN * BK];

  const int tid = threadIdx.x;
  const int lane = tid & 63;
  const int w = tid >> 6;
  const int wr = (w >> 1) * 64;
  const int wc = (w & 1) * 64;
  const int l15 = lane & 15;
  const int l4 = lane >> 4;

  f32x4 acc[4][4] = {};

  for (int k0 = 0; k0 < K; k0 += BK) {
    // ---- stage A via global_load_lds (linear LDS, source pre-swizzled) ----
#pragma unroll
    for (int it = 0; it < 4; ++it) {
      int c = it * 256 + tid;
      int r = c >> 3, kc = c & 7;
      int kcs = kc ^ (r & 7);  // XOR swizzle chunk within row (16B chunks)
      const unsigned short* src = A + (size_t)(row0 + r) * lda + k0 + kcs * 8;
      load_lds16(src, ((char*)Asm) + (size_t)(it * 256 + w * 64) * 16);
    }
    // ---- stage B: f32 load (coalesced along n), convert, swizzled LDS transpose ----
#pragma unroll
    for (int i = 0; i < 4; ++i) {
      int q = i * 256 + tid;
      int kp = q >> 5, hq = q & 31;
      const float* bsrc = B_e + (size_t)(k0 + 2 * kp) * ldb + n0 + 4 * hq;
      float4 va = *(const float4*)bsrc;
      float4 vb = *(const float4*)(bsrc + ldb);
      const float* pa = (const float*)&va;
      const float* pb = (const float*)&vb;
#pragma unroll
      for (int j = 0; j < 4; ++j) {
        int n = 4 * hq + j;
        int g = ((n >> 2) & 7) << 3;
        int koff = (2 * kp) ^ g;
        unsigned packed = (unsigned)f2b(pa[j]) | ((unsigned)f2b(pb[j]) << 16);
        *(unsigned*)((char*)Bsm + ((size_t)n * BK + koff) * 2) = packed;
      }
    }
    __syncthreads();
#pragma unroll
    for (int kk = 0; kk < 2; ++kk) {
      bf16x8 a[4], b[4];
#pragma unroll
      for (int m = 0; m < 4; ++m) {
        int row = wr + m * 16 + l15;
        int achunk = (kk * 4 + l4) ^ (l15 & 7);
        a[m] = *(const bf16x8*)&Asm[row * BK + achunk * 8];
      }
#pragma unroll
      for (int n = 0; n < 4; ++n) {
        int nl = wc + n * 16 + l15;
        int g = ((nl >> 2) & 7) << 3;
        int koff = (kk * 32 + l4 * 8) ^ g;
        b[n] = *(const bf16x8*)&Bsm[nl * BK + koff];
      }
#pragma unroll
      for (int m = 0; m < 4; ++m)
#pragma unroll
        for (int n = 0; n < 4; ++n)
          acc[m][n] =
              __builtin_amdgcn_mfma_f32_16x16x32_bf16(a[m], b[n], acc[m][n], 0, 0, 0);
    }
    __syncthreads();
  }

  // ---- epilogue: bias (+gelu), store ----
  const float* bias_e = bias + (long)e * strideBias;
#pragma unroll
  for (int m = 0; m < 4; ++m) {
#pragma unroll
    for (int i = 0; i < 4; ++i) {
      int r = wr + m * 16 + l4 * 4 + i;
      if (r < rows) {
        size_t grow = (size_t)(row0 + r) * ldc;
#pragma unroll
        for (int n = 0; n < 4; ++n) {
          int cl = wc + n * 16 + l15;
          int cg = n0 + cl;
          float v = acc[m][n][i] + bias_e[cg];
          if (GELU) v = 0.5f * v * (1.0f + erff(v * 0.70710678118654752f));
          if (OUTBF16)
            ((unsigned short*)Cout)[grow + cg] = f2b(v);
          else
            ((float*)Cout)[grow + cg] = v;
        }
      }
    }
  }
}

// ---------------- combine: out[b] = s0*Y[p0] + s1*Y[p1] ----------------
__global__ __launch_bounds__(256) void combine_kernel(
    const float* __restrict__ Y, const int* __restrict__ pos_of,
    const float* __restrict__ sc2, float* __restrict__ out) {
  int b = blockIdx.x;
  int c = threadIdx.x * 4;
  int p0 = pos_of[b * 2], p1 = pos_of[b * 2 + 1];
  float s0 = sc2[b * 2], s1 = sc2[b * 2 + 1];
  float4 y0 = *(const float4*)(Y + (size_t)p0 * DMODEL + c);
  float4 y1 = *(const float4*)(Y + (size_t)p1 * DMODEL + c);
  float4 o;
  o.x = s0 * y0.x + s1 * y1.x;
  o.y = s0 * y0.y + s1 * y1.y;
  o.z = s0 * y0.z + s1 * y1.z;
  o.w = s0 * y0.w + s1 * y1.w;
  *(float4*)(out + (size_t)b * DMODEL + c) = o;
}

extern "C" void kernel_launch(void* const* d_in, const int* in_sizes, int n_in,
                              void* d_out, int out_size, void* d_ws, size_t ws_size,
                              hipStream_t stream) {
  const float* x = (const float*)d_in[0];
  const float* gw = (const float*)d_in[1];
  const float* gb = (const float*)d_in[2];
  const float* w1 = (const float*)d_in[3];
  const float* b1 = (const float*)d_in[4];
  const float* w2 = (const float*)d_in[5];
  const float* b2 = (const float*)d_in[6];
  float* out = (float*)d_out;
  char* ws = (char*)d_ws;

  int* counts = (int*)(ws + 0);
  int* cursors = (int*)(ws + 64);
  int* ntiles = (int*)(ws + 128);
  int* offsets = (int*)(ws + 192);
  int* tile_map = (int*)(ws + 256);
  int* idx2 = (int*)(ws + 4096);
  float* sc2 = (float*)(ws + 20480);
  int* pos_of = (int*)(ws + 36864);
  int* row_of = (int*)(ws + 53248);
  unsigned short* Xp = (unsigned short*)(ws + 131072);      // 4224x1024 bf16
  unsigned short* H1 = (unsigned short*)(ws + 8781824);     // 4224x4096 bf16
  float* Y = (float*)(ws + 43384832);                       // 4224x1024 f32
  if (ws_size < 60686336ULL) return;

  hipMemsetAsync(counts, 0, 64, stream);
  gate_kernel<<<B_TOK / 4, 256, 0, stream>>>(x, gw, gb, idx2, sc2, counts);
  plan_kernel<<<1, 1, 0, stream>>>(counts, offsets, tile_map, ntiles, cursors);
  scatter_kernel<<<(B_TOK * TOPK) / 256, 256, 0, stream>>>(idx2, offsets, cursors,
                                                           pos_of, row_of);
  gather_kernel<<<B_TOK * TOPK, 256, 0, stream>>>(x, row_of, Xp);
  gemm_kernel<true, true><<<MAX_TILES * (HDIM / BN), 256, 0, stream>>>(
      Xp, DMODEL, w1, (long)DMODEL * HDIM, HDIM, b1, HDIM, H1, HDIM, tile_map,
      ntiles, HDIM, DMODEL);
  gemm_kernel<false, false><<<MAX_TILES * (DMODEL / BN), 256, 0, stream>>>(
      H1, HDIM, w2, (long)HDIM * DMODEL, DMODEL, b2, DMODEL, Y, DMODEL, tile_map,
      ntiles, DMODEL, HDIM);
  combine_kernel<<<B_TOK, 256, 0, stream>>>(Y, pos_of, sc2, out);
}

// Round 2
// 324.357 us; speedup vs baseline: 1.1407x; 1.1407x over previous
//
#include <hip/hip_runtime.h>
#include <math.h>

#define B_TOK 2048
#define DMODEL 1024
#define HDIM 4096
#define NEXP 8
#define TOPK 2

#define BM 128
#define BK 64
#define MAX_TILES 40

typedef __attribute__((ext_vector_type(8))) short bf16x8;
typedef __attribute__((ext_vector_type(4))) float f32x4;

__device__ __forceinline__ unsigned short f2b(float f) {
  unsigned u = __builtin_bit_cast(unsigned, f);
  unsigned r = (u + 0x7FFFu + ((u >> 16) & 1u)) >> 16;
  return (unsigned short)r;
}

__device__ __forceinline__ void load_lds16(const void* g, void* l) {
  __builtin_amdgcn_global_load_lds(
      (const __attribute__((address_space(1))) unsigned int*)g,
      (__attribute__((address_space(3))) unsigned int*)l, 16, 0, 0);
}

// ---------------- gate: logits (f64 accum) -> top2 -> softmax ----------------
__global__ __launch_bounds__(256) void gate_kernel(
    const float* __restrict__ x, const float* __restrict__ gw,
    const float* __restrict__ gb, int* __restrict__ idx2,
    float* __restrict__ sc2, int* __restrict__ counts) {
  int lane = threadIdx.x & 63;
  int w = threadIdx.x >> 6;
  int b = blockIdx.x * 4 + w;
  double acc[NEXP];
#pragma unroll
  for (int e = 0; e < NEXP; ++e) acc[e] = 0.0;
  const float* xr = x + (size_t)b * DMODEL;
#pragma unroll
  for (int i = 0; i < 4; ++i) {
    float4 xv = *(const float4*)(xr + i * 256 + lane * 4);
#pragma unroll
    for (int e = 0; e < NEXP; ++e) {
      float4 wv = *(const float4*)(gw + e * DMODEL + i * 256 + lane * 4);
      acc[e] += (double)xv.x * wv.x + (double)xv.y * wv.y +
                (double)xv.z * wv.z + (double)xv.w * wv.w;
    }
  }
#pragma unroll
  for (int e = 0; e < NEXP; ++e) {
    double v = acc[e];
    for (int o = 1; o < 64; o <<= 1) v += __shfl_xor(v, o, 64);
    acc[e] = v + (double)gb[e];
  }
  if (lane == 0) {
    int i0 = 0;
    double v0 = acc[0];
#pragma unroll
    for (int e = 1; e < NEXP; ++e)
      if (acc[e] > v0) { v0 = acc[e]; i0 = e; }
    int i1 = -1;
    double v1 = -1e300;
#pragma unroll
    for (int e = 0; e < NEXP; ++e)
      if (e != i0 && acc[e] > v1) { v1 = acc[e]; i1 = e; }
    double t = exp(v1 - v0);
    float s0 = (float)(1.0 / (1.0 + t));
    float s1 = (float)(t / (1.0 + t));
    idx2[b * 2] = i0;
    idx2[b * 2 + 1] = i1;
    sc2[b * 2] = s0;
    sc2[b * 2 + 1] = s1;
    atomicAdd(&counts[i0], 1);
    atomicAdd(&counts[i1], 1);
  }
}

// ---------------- plan: prefix offsets + tile map (1 thread) ----------------
__global__ void plan_kernel(const int* __restrict__ counts, int* __restrict__ offsets,
                            int* __restrict__ tile_map, int* __restrict__ ntiles,
                            int* __restrict__ cursors) {
  int off = 0;
  offsets[0] = 0;
  for (int e = 0; e < NEXP; ++e) {
    off += counts[e];
    offsets[e + 1] = off;
    cursors[e] = 0;
  }
  int tt = 0;
  for (int e = 0; e < NEXP; ++e) {
    int cnt = counts[e];
    int base = offsets[e];
    for (int t = 0; t * BM < cnt; ++t) {
      tile_map[tt * 4 + 0] = e;
      tile_map[tt * 4 + 1] = base + t * BM;
      tile_map[tt * 4 + 2] = (cnt - t * BM) < BM ? (cnt - t * BM) : BM;
      tile_map[tt * 4 + 3] = 0;
      ++tt;
    }
  }
  *ntiles = tt;
}

// ---------------- scatter: (b,k) -> pos; also pos->token/score ----------------
__global__ __launch_bounds__(256) void scatter_kernel(
    const int* __restrict__ idx2, const float* __restrict__ sc2,
    const int* __restrict__ offsets, int* __restrict__ cursors,
    int* __restrict__ pos_of, int* __restrict__ row_of, float* __restrict__ s_of) {
  int t = blockIdx.x * 256 + threadIdx.x;
  if (t < B_TOK * TOPK) {
    int e = idx2[t];
    int p = offsets[e] + atomicAdd(&cursors[e], 1);
    pos_of[t] = p;
    row_of[p] = t >> 1;
    s_of[p] = sc2[t];
  }
}

// ---------------- gather: permuted bf16 activations ----------------
__global__ __launch_bounds__(256) void gather_kernel(
    const float* __restrict__ x, const int* __restrict__ row_of,
    unsigned short* __restrict__ Xp) {
  int r = blockIdx.x;
  int tok = row_of[r];
  int c = threadIdx.x * 4;
  float4 v = *(const float4*)(x + (size_t)tok * DMODEL + c);
  ushort4 o = make_ushort4(f2b(v.x), f2b(v.y), f2b(v.z), f2b(v.w));
  *(ushort4*)(Xp + (size_t)r * DMODEL + c) = o;
}

// ---------------- transpose+convert: W[e][k][n] f32 -> Wt[e][n][k] bf16 ----------------
__global__ __launch_bounds__(256) void convT_kernel(
    const float* __restrict__ W, unsigned short* __restrict__ Wt, int Kd, int Nd,
    int tilesN) {
  __shared__ __align__(16) unsigned short t[64][68];
  int bidx = blockIdx.x;
  int nt = bidx % tilesN;
  int r2 = bidx / tilesN;
  int tilesK = Kd >> 6;
  int kt = r2 % tilesK;
  int e = r2 / tilesK;
  int tid = threadIdx.x;
  const float* src = W + (long)e * Kd * Nd + (long)(kt * 64) * Nd + nt * 64;
#pragma unroll
  for (int i = 0; i < 4; ++i) {
    int idx = i * 256 + tid;
    int r = idx >> 4, c4 = idx & 15;
    float4 v = *(const float4*)(src + (long)r * Nd + c4 * 4);
    ushort4 o = make_ushort4(f2b(v.x), f2b(v.y), f2b(v.z), f2b(v.w));
    *(ushort4*)&t[r][c4 * 4] = o;
  }
  __syncthreads();
  unsigned short* dst = Wt + (long)e * Nd * Kd + (long)(nt * 64) * Kd + kt * 64;
#pragma unroll
  for (int i = 0; i < 4; ++i) {
    int idx = i * 256 + tid;
    int rn = idx >> 4, ck = idx & 15;
    ushort4 o = make_ushort4(t[ck * 4 + 0][rn], t[ck * 4 + 1][rn],
                             t[ck * 4 + 2][rn], t[ck * 4 + 3][rn]);
    *(ushort4*)(dst + (long)rn * Kd + ck * 4) = o;
  }
}

// ---------------- grouped GEMM (m97 structure): A[rows][K] bf16 x Bt[E][N][K] bf16 ----------------
// OMODE 0: f32 store; 1: bf16 store; 2: f32 atomicAdd of s*(acc+bias) into out[token]
template <int BN_, int WM, int WN, bool GELU, int OMODE>
__global__ __launch_bounds__(256) void gemm_bt(
    const unsigned short* __restrict__ A, int lda,
    const unsigned short* __restrict__ Bt, long strideB,
    const float* __restrict__ bias, int strideBias, void* __restrict__ Cout,
    int ldc, const int* __restrict__ row_of, const float* __restrict__ s_of,
    const int* __restrict__ tile_map, const int* __restrict__ ntiles, int N,
    int K) {
  const int nb = N / BN_;
  const int tile = blockIdx.x / nb;
  if (tile >= *ntiles) return;
  const int ct = blockIdx.x % nb;
  const int e = tile_map[tile * 4 + 0];
  const int row0 = tile_map[tile * 4 + 1];
  const int rows = tile_map[tile * 4 + 2];
  const int n0 = ct * BN_;
  const unsigned short* B_e = Bt + (long)e * strideB + (long)n0 * K;

  __shared__ __align__(16) unsigned short Asm[BM * BK];
  __shared__ __align__(16) unsigned short Bsm[BN_ * BK];

  const int tid = threadIdx.x;
  const int lane = tid & 63;
  const int w = tid >> 6;
  const int WTM = BM / WM, WTN = BN_ / WN;
  const int wr = (w / WN) * WTM;
  const int wc = (w % WN) * WTN;
  const int MR = WTM / 16, NR = WTN / 16;
  const int l15 = lane & 15;
  const int l4 = lane >> 4;

  f32x4 acc[MR][NR] = {};

  for (int k0 = 0; k0 < K; k0 += BK) {
    // A: 128x64 bf16 = 16KB -> 4 wave-wide 16B loads per thread-slot
#pragma unroll
    for (int it = 0; it < 4; ++it) {
      int c = it * 256 + tid;
      int r = c >> 3, kc = c & 7;
      int kcs = kc ^ (r & 7);
      load_lds16(A + (size_t)(row0 + r) * lda + k0 + kcs * 8,
                 ((char*)Asm) + (size_t)(it * 256 + w * 64) * 16);
    }
    // B: BN_ x 64 bf16 -> BN_/32 loads
#pragma unroll
    for (int it = 0; it < BN_ / 32; ++it) {
      int c = it * 256 + tid;
      int r = c >> 3, kc = c & 7;
      int kcs = kc ^ (r & 7);
      load_lds16(B_e + (size_t)r * K + k0 + kcs * 8,
                 ((char*)Bsm) + (size_t)(it * 256 + w * 64) * 16);
    }
    __syncthreads();
#pragma unroll
    for (int kk = 0; kk < 2; ++kk) {
      bf16x8 a[MR], b[NR];
#pragma unroll
      for (int m = 0; m < MR; ++m) {
        int row = wr + m * 16 + l15;
        int ch = (kk * 4 + l4) ^ (l15 & 7);
        a[m] = *(const bf16x8*)&Asm[row * BK + ch * 8];
      }
#pragma unroll
      for (int n = 0; n < NR; ++n) {
        int row = wc + n * 16 + l15;
        int ch = (kk * 4 + l4) ^ (l15 & 7);
        b[n] = *(const bf16x8*)&Bsm[row * BK + ch * 8];
      }
#pragma unroll
      for (int m = 0; m < MR; ++m)
#pragma unroll
        for (int n = 0; n < NR; ++n)
          acc[m][n] =
              __builtin_amdgcn_mfma_f32_16x16x32_bf16(a[m], b[n], acc[m][n], 0, 0, 0);
    }
    __syncthreads();
  }

  const float* bias_e = bias + (long)e * strideBias;
#pragma unroll
  for (int m = 0; m < MR; ++m) {
#pragma unroll
    for (int i = 0; i < 4; ++i) {
      int r = wr + m * 16 + l4 * 4 + i;
      if (r < rows) {
        if (OMODE == 2) {
          int tok = row_of[row0 + r];
          float s = s_of[row0 + r];
          float* op = (float*)Cout + (size_t)tok * ldc;
#pragma unroll
          for (int n = 0; n < NR; ++n) {
            int cg = n0 + wc + n * 16 + l15;
            float v = acc[m][n][i] + bias_e[cg];
            atomicAdd(&op[cg], s * v);
          }
        } else {
          size_t grow = (size_t)(row0 + r) * ldc;
#pragma unroll
          for (int n = 0; n < NR; ++n) {
            int cg = n0 + wc + n * 16 + l15;
            float v = acc[m][n][i] + bias_e[cg];
            if (GELU) v = 0.5f * v * (1.0f + erff(v * 0.70710678118654752f));
            if (OMODE == 1)
              ((unsigned short*)Cout)[grow + cg] = f2b(v);
            else
              ((float*)Cout)[grow + cg] = v;
          }
        }
      }
    }
  }
}

// ================= fallback path (round-1, proven) =================
template <bool GELU, bool OUTBF16>
__global__ __launch_bounds__(256) void gemm_kernel(
    const unsigned short* __restrict__ A, int lda, const float* __restrict__ Bw,
    long strideB, int ldb, const float* __restrict__ bias, int strideBias,
    void* __restrict__ Cout, int ldc, const int* __restrict__ tile_map,
    const int* __restrict__ ntiles, int N, int K) {
  const int nb = N / 128;
  const int tile = blockIdx.x / nb;
  if (tile >= *ntiles) return;
  const int ct = blockIdx.x % nb;
  const int e = tile_map[tile * 4 + 0];
  const int row0 = tile_map[tile * 4 + 1];
  const int rows = tile_map[tile * 4 + 2];
  const float* B_e = Bw + (long)e * strideB;
  const int n0 = ct * 128;

  __shared__ __align__(16) unsigned short Asm[BM * BK];
  __shared__ __align__(16) unsigned short Bsm[128 * BK];

  const int tid = threadIdx.x;
  const int lane = tid & 63;
  const int w = tid >> 6;
  const int wr = (w >> 1) * 64;
  const int wc = (w & 1) * 64;
  const int l15 = lane & 15;
  const int l4 = lane >> 4;

  f32x4 acc[4][4] = {};

  for (int k0 = 0; k0 < K; k0 += BK) {
#pragma unroll
    for (int it = 0; it < 4; ++it) {
      int c = it * 256 + tid;
      int r = c >> 3, kc = c & 7;
      int kcs = kc ^ (r & 7);
      load_lds16(A + (size_t)(row0 + r) * lda + k0 + kcs * 8,
                 ((char*)Asm) + (size_t)(it * 256 + w * 64) * 16);
    }
#pragma unroll
    for (int i = 0; i < 4; ++i) {
      int q = i * 256 + tid;
      int kp = q >> 5, hq = q & 31;
      const float* bsrc = B_e + (size_t)(k0 + 2 * kp) * ldb + n0 + 4 * hq;
      float4 va = *(const float4*)bsrc;
      float4 vb = *(const float4*)(bsrc + ldb);
      const float* pa = (const float*)&va;
      const float* pb = (const float*)&vb;
#pragma unroll
      for (int j = 0; j < 4; ++j) {
        int n = 4 * hq + j;
        int g = ((n >> 2) & 7) << 3;
        int koff = (2 * kp) ^ g;
        unsigned packed = (unsigned)f2b(pa[j]) | ((unsigned)f2b(pb[j]) << 16);
        *(unsigned*)((char*)Bsm + ((size_t)n * BK + koff) * 2) = packed;
      }
    }
    __syncthreads();
#pragma unroll
    for (int kk = 0; kk < 2; ++kk) {
      bf16x8 a[4], b[4];
#pragma unroll
      for (int m = 0; m < 4; ++m) {
        int row = wr + m * 16 + l15;
        int achunk = (kk * 4 + l4) ^ (l15 & 7);
        a[m] = *(const bf16x8*)&Asm[row * BK + achunk * 8];
      }
#pragma unroll
      for (int n = 0; n < 4; ++n) {
        int nl = wc + n * 16 + l15;
        int g = ((nl >> 2) & 7) << 3;
        int koff = (kk * 32 + l4 * 8) ^ g;
        b[n] = *(const bf16x8*)&Bsm[nl * BK + koff];
      }
#pragma unroll
      for (int m = 0; m < 4; ++m)
#pragma unroll
        for (int n = 0; n < 4; ++n)
          acc[m][n] =
              __builtin_amdgcn_mfma_f32_16x16x32_bf16(a[m], b[n], acc[m][n], 0, 0, 0);
    }
    __syncthreads();
  }

  const float* bias_e = bias + (long)e * strideBias;
#pragma unroll
  for (int m = 0; m < 4; ++m) {
#pragma unroll
    for (int i = 0; i < 4; ++i) {
      int r = wr + m * 16 + l4 * 4 + i;
      if (r < rows) {
        size_t grow = (size_t)(row0 + r) * ldc;
#pragma unroll
        for (int n = 0; n < 4; ++n) {
          int cl = wc + n * 16 + l15;
          int cg = n0 + cl;
          float v = acc[m][n][i] + bias_e[cg];
          if (GELU) v = 0.5f * v * (1.0f + erff(v * 0.70710678118654752f));
          if (OUTBF16)
            ((unsigned short*)Cout)[grow + cg] = f2b(v);
          else
            ((float*)Cout)[grow + cg] = v;
        }
      }
    }
  }
}

__global__ __launch_bounds__(256) void combine_kernel(
    const float* __restrict__ Y, const int* __restrict__ pos_of,
    const float* __restrict__ sc2, float* __restrict__ out) {
  int b = blockIdx.x;
  int c = threadIdx.x * 4;
  int p0 = pos_of[b * 2], p1 = pos_of[b * 2 + 1];
  float s0 = sc2[b * 2], s1 = sc2[b * 2 + 1];
  float4 y0 = *(const float4*)(Y + (size_t)p0 * DMODEL + c);
  float4 y1 = *(const float4*)(Y + (size_t)p1 * DMODEL + c);
  float4 o;
  o.x = s0 * y0.x + s1 * y1.x;
  o.y = s0 * y0.y + s1 * y1.y;
  o.z = s0 * y0.z + s1 * y1.z;
  o.w = s0 * y0.w + s1 * y1.w;
  *(float4*)(out + (size_t)b * DMODEL + c) = o;
}

extern "C" void kernel_launch(void* const* d_in, const int* in_sizes, int n_in,
                              void* d_out, int out_size, void* d_ws, size_t ws_size,
                              hipStream_t stream) {
  const float* x = (const float*)d_in[0];
  const float* gw = (const float*)d_in[1];
  const float* gb = (const float*)d_in[2];
  const float* w1 = (const float*)d_in[3];
  const float* b1 = (const float*)d_in[4];
  const float* w2 = (const float*)d_in[5];
  const float* b2 = (const float*)d_in[6];
  float* out = (float*)d_out;
  char* ws = (char*)d_ws;

  int* counts = (int*)(ws + 0);
  int* cursors = (int*)(ws + 64);
  int* ntiles = (int*)(ws + 128);
  int* offsets = (int*)(ws + 192);
  int* tile_map = (int*)(ws + 256);
  int* idx2 = (int*)(ws + 4096);
  float* sc2 = (float*)(ws + 20480);
  int* pos_of = (int*)(ws + 36864);
  int* row_of = (int*)(ws + 53248);
  float* s_of = (float*)(ws + 73728);
  unsigned short* Xp = (unsigned short*)(ws + 131072);    // 4224x1024 bf16
  unsigned short* H1 = (unsigned short*)(ws + 8781824);   // 4224x4096 bf16
  float* Y = (float*)(ws + 43384832);                     // fallback: 4224x1024 f32
  unsigned short* Wt = (unsigned short*)(ws + 43384832);  // fast: 8x4096x1024 bf16
  if (ws_size < 60686336ULL) return;
  const bool fast = ws_size >= 110493696ULL;

  hipMemsetAsync(counts, 0, 64, stream);
  if (fast) hipMemsetAsync(out, 0, (size_t)B_TOK * DMODEL * 4, stream);
  gate_kernel<<<B_TOK / 4, 256, 0, stream>>>(x, gw, gb, idx2, sc2, counts);
  plan_kernel<<<1, 1, 0, stream>>>(counts, offsets, tile_map, ntiles, cursors);
  scatter_kernel<<<(B_TOK * TOPK) / 256, 256, 0, stream>>>(idx2, sc2, offsets,
                                                           cursors, pos_of, row_of,
                                                           s_of);
  gather_kernel<<<B_TOK * TOPK, 256, 0, stream>>>(x, row_of, Xp);

  if (fast) {
    // w1 [E][D][H] f32 -> Wt [E][H][D] bf16
    convT_kernel<<<NEXP * (DMODEL / 64) * (HDIM / 64), 256, 0, stream>>>(
        w1, Wt, DMODEL, HDIM, HDIM / 64);
    gemm_bt<128, 2, 2, true, 1><<<MAX_TILES * (HDIM / 128), 256, 0, stream>>>(
        Xp, DMODEL, Wt, (long)HDIM * DMODEL, b1, HDIM, H1, HDIM, nullptr, nullptr,
        tile_map, ntiles, HDIM, DMODEL);
    // w2 [E][H][D] f32 -> Wt [E][D][H] bf16 (reuse buffer)
    convT_kernel<<<NEXP * (HDIM / 64) * (DMODEL / 64), 256, 0, stream>>>(
        w2, Wt, HDIM, DMODEL, DMODEL / 64);
    gemm_bt<64, 4, 1, false, 2><<<MAX_TILES * (DMODEL / 64), 256, 0, stream>>>(
        H1, HDIM, Wt, (long)DMODEL * HDIM, b2, DMODEL, out, DMODEL, row_of, s_of,
        tile_map, ntiles, DMODEL, HDIM);
  } else {
    gemm_kernel<true, true><<<MAX_TILES * (HDIM / 128), 256, 0, stream>>>(
        Xp, DMODEL, w1, (long)DMODEL * HDIM, HDIM, b1, HDIM, H1, HDIM, tile_map,
        ntiles, HDIM, DMODEL);
    gemm_kernel<false, false><<<MAX_TILES * (DMODEL / 128), 256, 0, stream>>>(
        H1, HDIM, w2, (long)HDIM * DMODEL, DMODEL, b2, DMODEL, Y, DMODEL, tile_map,
        ntiles, DMODEL, HDIM);
    combine_kernel<<<B_TOK, 256, 0, stream>>>(Y, pos_of, sc2, out);
  }
}